// Round 9
// baseline (178.052 us; speedup 1.0000x reference)
//
#include <hip/hip_runtime.h>

#define DZ 512
#define DT 66048
#define NSTRIP 1032  // 64-col strips
#define SV_JITTER 1e-4f

typedef __attribute__((ext_vector_type(8))) short bf8;
typedef __attribute__((ext_vector_type(4))) short bf4;
typedef __attribute__((ext_vector_type(4))) float f4;

__device__ __forceinline__ short f2bf(float f) {
  unsigned u = __builtin_bit_cast(unsigned, f);
  return (short)((u + 0x7FFFu + ((u >> 16) & 1u)) >> 16);
}

__device__ __forceinline__ bf8 cvt8(float4 a, float4 b) {
  bf8 r = { f2bf(a.x), f2bf(a.y), f2bf(a.z), f2bf(a.w),
            f2bf(b.x), f2bf(b.y), f2bf(b.z), f2bf(b.w) };
  return r;
}

// tril/jitter cvt: element t has k-index kbase+t
__device__ __forceinline__ bf8 cvt8_tril(float4 x, float4 y, int kbase, int diag) {
  float v[8] = {x.x, x.y, x.z, x.w, y.x, y.y, y.z, y.w};
  bf8 r;
  #pragma unroll
  for (int t = 0; t < 8; ++t) {
    int k = kbase + t;
    float val = (k < diag) ? v[t] : ((k == diag) ? v[t] + SV_JITTER : 0.f);
    r[t] = f2bf(val);
  }
  return r;
}

// 256 persistent blocks (1/CU) x 1024 threads (16 waves = 4/SIMD).
// A (eps_z, 16 samples/wave x K=512) lives in REGISTERS (af[16], loaded once).
// Per strip (64 cols): B panel (64 rows x 2KB fp32, fully sequential) is
// cooperatively staged into double-buffered XOR-swizzled bf16 LDS; compute
// phase has ZERO VMEM (ds_read_b128 + MFMA only). tril/jitter applied at
// stage time. Wave (ws=sample grp, wc=32-col half).
// acc layout per mfma_f32_16x16x32_bf16: col=lane&15, row=4*(lane>>4)+reg.
__global__ __launch_bounds__(1024)
void sv_kernel(const float* __restrict__ mv, const float* __restrict__ Lz,
               const float* __restrict__ Ly, const float* __restrict__ Lyz,
               const float* __restrict__ eps, float* __restrict__ out) {
  // panel: [64 rows][512 k] bf16, 1KB/row; 16B slot s at byte
  // row*1024 + ((s ^ (row&7))<<4)  (XOR swizzle kills stride-1KB conflicts)
  __shared__ short Bp[2][64 * 512];  // 2 x 64 KB

  const int tid = threadIdx.x;
  const int lane = tid & 63;
  const int wv = tid >> 6;
  const int lcol = lane & 15;
  const int q = lane >> 4;
  const int ws = wv >> 1;  // sample group (rows 16*ws..+15)
  const int wc = wv & 1;   // 32-col half of the strip
  const int b = blockIdx.x;

  float4 svA[4], svB[4];  // staged panel floats (live across compute)

  auto sissue = [&](int s, float4* sv, int h) {
    #pragma unroll
    for (int i = 0; i < 4; ++i) {
      const int f = (h * 4 + i) * 1024 + tid;  // float4 index in panel
      const int row = f >> 7;
      const int k0 = (f & 127) << 2;
      const int gc = s * 64 + row;
      const float* src = (gc < DZ) ? (Lz + (size_t)gc * DZ + k0)
                                   : (Lyz + (size_t)(gc - DZ) * DZ + k0);
      sv[i] = *(const float4*)src;
    }
  };
  auto swrite = [&](int s, short* buf, const float4* sv, int h) {
    #pragma unroll
    for (int i = 0; i < 4; ++i) {
      const int f = (h * 4 + i) * 1024 + tid;
      const int row = f >> 7;
      const int k0 = (f & 127) << 2;
      const int gc = s * 64 + row;
      const float v[4] = {sv[i].x, sv[i].y, sv[i].z, sv[i].w};
      bf4 w;
      if (gc < DZ) {  // z rows: tril + jitter at stage time
        #pragma unroll
        for (int t = 0; t < 4; ++t) {
          const int k = k0 + t;
          const float val = (k < gc) ? v[t] : ((k == gc) ? v[t] + SV_JITTER : 0.f);
          w[t] = f2bf(val);
        }
      } else {
        #pragma unroll
        for (int t = 0; t < 4; ++t) w[t] = f2bf(v[t]);
      }
      const int slot = k0 >> 3;
      const int off = (row << 10) + ((slot ^ (row & 7)) << 4) + ((k0 & 4) << 1);
      *(bf4*)((char*)buf + off) = w;
    }
  };
  auto readB = [&](const short* buf, int g, int kk) -> bf8 {
    const int rowIdx = wc * 32 + 16 * g + lcol;
    const int slot = kk * 4 + q;
    const int off = (rowIdx << 10) + ((slot ^ (rowIdx & 7)) << 4);
    return *(const bf8*)((const char*)buf + off);
  };

  // ---- prologue: start strip-0 panel stream, then load A into registers
  sissue(b, svA, 0);
  sissue(b, svB, 1);
  bf8 af[16];
  {
    const float* ar = eps + (size_t)(16 * ws + lcol) * DT + 8 * q;
    #pragma unroll
    for (int kk = 0; kk < 16; ++kk) {
      float4 x = *(const float4*)(ar + kk * 32);
      float4 y = *(const float4*)(ar + kk * 32 + 4);
      af[kk] = cvt8(x, y);
    }
  }
  swrite(b, Bp[0], svA, 0);  // waits only the 8 panel loads (oldest)
  swrite(b, Bp[0], svB, 1);
  __syncthreads();

  #pragma unroll 1
  for (int js = 0; js < 5; ++js) {
    const int s = b + 256 * js;
    if (s >= NSTRIP) break;
    const bool is_y = (s >= 8);
    const int sn = s + 256;
    const bool have_next = (sn < NSTRIP);

    // diag loads FIRST (oldest in vmcnt queue -> their wait never drains sv)
    float4 dax, day, b0x, b0y, b1x, b1y;
    int n = 0;
    if (is_y) {
      n = 2 * s - 16 + wc;  // this wave's 32x32 Ly block
      const float* pa = eps + (size_t)(16 * ws + lcol) * DT + DZ + (size_t)n * 32 + 8 * q;
      dax = *(const float4*)pa; day = *(const float4*)(pa + 4);
      const float* pb0 = Ly + ((size_t)n * 32 + lcol) * 32 + 8 * q;
      b0x = *(const float4*)pb0; b0y = *(const float4*)(pb0 + 4);
      const float* pb1 = Ly + ((size_t)n * 32 + 16 + lcol) * 32 + 8 * q;
      b1x = *(const float4*)pb1; b1y = *(const float4*)(pb1 + 4);
    }
    if (have_next) { sissue(sn, svA, 0); sissue(sn, svB, 1); }

    bf8 afd{}, bfd0{}, bfd1{};
    if (is_y) {  // convert now: frees the 24 raw regs before the main loop
      afd = cvt8(dax, day);
      bfd0 = cvt8_tril(b0x, b0y, 8 * q, lcol);
      bfd1 = cvt8_tril(b1x, b1y, 8 * q, 16 + lcol);
    }

    // ---- compute: zero VMEM (A in regs, B in LDS)
    const short* buf = Bp[js & 1];
    f4 acc0 = f4{0.f, 0.f, 0.f, 0.f};
    f4 acc1 = f4{0.f, 0.f, 0.f, 0.f};
    #pragma unroll
    for (int kk = 0; kk < 16; ++kk) {
      const bf8 b0 = readB(buf, 0, kk);
      const bf8 b1 = readB(buf, 1, kk);
      acc0 = __builtin_amdgcn_mfma_f32_16x16x32_bf16(af[kk], b0, acc0, 0, 0, 0);
      acc1 = __builtin_amdgcn_mfma_f32_16x16x32_bf16(af[kk], b1, acc1, 0, 0, 0);
    }
    if (is_y) {
      acc0 = __builtin_amdgcn_mfma_f32_16x16x32_bf16(afd, bfd0, acc0, 0, 0, 0);
      acc1 = __builtin_amdgcn_mfma_f32_16x16x32_bf16(afd, bfd1, acc1, 0, 0, 0);
    }

    // ---- epilogue: both 64B halves of each 128B line written back-to-back
    {
      const int colbase = s * 64 + wc * 32;
      const int c0 = colbase + lcol, c1 = colbase + 16 + lcol;
      const float m0 = mv[c0], m1 = mv[c1];
      #pragma unroll
      for (int rr = 0; rr < 4; ++rr) {
        const size_t rowoff = (size_t)(16 * ws + 4 * q + rr) * DT;
        out[rowoff + c0] = acc0[rr] + m0;
        out[rowoff + c1] = acc1[rr] + m1;
      }
    }

    __syncthreads();  // all waves done reading Bp[js&1]; drains sv (needed next)
    if (have_next) {
      short* nbuf = Bp[(js & 1) ^ 1];
      swrite(sn, nbuf, svA, 0);
      swrite(sn, nbuf, svB, 1);
    }
    __syncthreads();  // staged panel visible to all
  }
}

extern "C" void kernel_launch(void* const* d_in, const int* in_sizes, int n_in,
                              void* d_out, int out_size, void* d_ws, size_t ws_size,
                              hipStream_t stream) {
  const float* m   = (const float*)d_in[0];
  const float* Lz  = (const float*)d_in[1];
  const float* Ly  = (const float*)d_in[2];
  const float* Lyz = (const float*)d_in[3];
  const float* eps = (const float*)d_in[4];
  float* out = (float*)d_out;
  sv_kernel<<<dim3(256), dim3(1024), 0, stream>>>(m, Lz, Ly, Lyz, eps, out);
}

// Round 10
// 52.347 us; speedup vs baseline: 3.4014x; 3.4014x over previous
//
#include <hip/hip_runtime.h>

#define DZ 512
#define DT 66048
#define NT 4128  // 16-col output tiles
#define SV_JITTER 1e-4f

typedef __attribute__((ext_vector_type(8))) short bf8;
typedef __attribute__((ext_vector_type(4))) float f4;

__device__ __forceinline__ short f2bf(float f) {
  unsigned u = __builtin_bit_cast(unsigned, f);
  return (short)((u + 0x7FFFu + ((u >> 16) & 1u)) >> 16);
}

__device__ __forceinline__ bf8 cvt8(float4 a, float4 b) {
  bf8 r = { f2bf(a.x), f2bf(a.y), f2bf(a.z), f2bf(a.w),
            f2bf(b.x), f2bf(b.y), f2bf(b.z), f2bf(b.w) };
  return r;
}

// tril/jitter cvt: element t has k-index kbase+t
__device__ __forceinline__ bf8 cvt8_tril(float4 x, float4 y, int kbase, int diag) {
  float v[8] = {x.x, x.y, x.z, x.w, y.x, y.y, y.z, y.w};
  bf8 r;
  #pragma unroll
  for (int t = 0; t < 8; ++t) {
    int k = kbase + t;
    float val = (k < diag) ? v[t] : ((k == diag) ? v[t] + SV_JITTER : 0.f);
    r[t] = f2bf(val);
  }
  return r;
}

// One 16-col tile, all 128 samples (8 M-frags). B read once chip-wide.
// B register-prefetched 6-DEEP (b0..b5, rotation j%6); A single-buffered.
// acc layout per mfma_f32_16x16x32_bf16: col=lane&15, row=4*(lane>>4)+reg.
template <bool IS_Z>
__device__ __forceinline__ void process_tile(
    int col0, int lcol, int q, int lane, const short* __restrict__ Afrag,
    const float* __restrict__ mv, const float* __restrict__ Lz,
    const float* __restrict__ Ly, const float* __restrict__ Lyz,
    const float* __restrict__ eps, float* __restrict__ out) {
  const int colL = col0 + lcol;
  const float* bptr = IS_Z ? (Lz + (size_t)colL * DZ)
                           : (Lyz + (size_t)(colL - DZ) * DZ);
  const int bdiag = colL;  // tril diag (IS_Z only)

  f4 acc[8];
  #pragma unroll
  for (int mi = 0; mi < 8; ++mi) acc[mi] = f4{0.f, 0.f, 0.f, 0.f};

  float4 b0x, b0y, b1x, b1y, b2x, b2y, b3x, b3y, b4x, b4y, b5x, b5y;
  bf8 a[8];  // single A buffer (register-budget cap for 4 waves/SIMD)

  auto loadB = [&](int kk, float4& x, float4& y) {
    const float* p = bptr + kk * 32 + 8 * q;
    x = *(const float4*)p;
    y = *(const float4*)(p + 4);
  };
  auto loadA = [&](int kk) {
    #pragma unroll
    for (int mi = 0; mi < 8; ++mi)
      a[mi] = *(const bf8*)&Afrag[(kk * 8 + mi) * 512 + lane * 8];
  };
  auto mk = [&](float4 x, float4 y, int kb) {
    return IS_Z ? cvt8_tril(x, y, kb, bdiag) : cvt8(x, y);
  };
  auto domfma = [&](bf8 bf) {
    #pragma unroll
    for (int mi = 0; mi < 8; ++mi)
      acc[mi] = __builtin_amdgcn_mfma_f32_16x16x32_bf16(a[mi], bf, acc[mi], 0, 0, 0);
  };

  // prologue: B 6-deep in flight
  loadB(0, b0x, b0y); loadB(1, b1x, b1y); loadB(2, b2x, b2y);
  loadB(3, b3x, b3y); loadB(4, b4x, b4y); loadB(5, b5x, b5y);

  // steps 0..9: consume buffer j%6, refill with K-step j+6
  { loadA(0); bf8 bf = mk(b0x, b0y, 0 * 32 + 8 * q); loadB(6,  b0x, b0y); domfma(bf); }
  { loadA(1); bf8 bf = mk(b1x, b1y, 1 * 32 + 8 * q); loadB(7,  b1x, b1y); domfma(bf); }
  { loadA(2); bf8 bf = mk(b2x, b2y, 2 * 32 + 8 * q); loadB(8,  b2x, b2y); domfma(bf); }
  { loadA(3); bf8 bf = mk(b3x, b3y, 3 * 32 + 8 * q); loadB(9,  b3x, b3y); domfma(bf); }
  { loadA(4); bf8 bf = mk(b4x, b4y, 4 * 32 + 8 * q); loadB(10, b4x, b4y); domfma(bf); }
  { loadA(5); bf8 bf = mk(b5x, b5y, 5 * 32 + 8 * q); loadB(11, b5x, b5y); domfma(bf); }
  { loadA(6); bf8 bf = mk(b0x, b0y, 6 * 32 + 8 * q); loadB(12, b0x, b0y); domfma(bf); }
  { loadA(7); bf8 bf = mk(b1x, b1y, 7 * 32 + 8 * q); loadB(13, b1x, b1y); domfma(bf); }
  { loadA(8); bf8 bf = mk(b2x, b2y, 8 * 32 + 8 * q); loadB(14, b2x, b2y); domfma(bf); }
  { loadA(9); bf8 bf = mk(b3x, b3y, 9 * 32 + 8 * q); loadB(15, b3x, b3y); domfma(bf); }

  // diag-step B prefetch (y tiles): issued behind the 6 outstanding refills
  float4 dbx{}, dby{};
  int nb = 0, dI = 0;
  if (!IS_Z) {
    nb = (col0 - DZ) >> 5;            // 32x32 Ly block
    dI = (col0 - DZ) & 31;            // tile's base row within block (0 or 16)
    const float* pb = Ly + ((size_t)nb * 32 + dI + lcol) * 32 + 8 * q;
    dbx = *(const float4*)pb; dby = *(const float4*)(pb + 4);
  }

  // steps 10..15: drain (buffers hold exactly K=10..15)
  { loadA(10); bf8 bf = mk(b4x, b4y, 10 * 32 + 8 * q); domfma(bf); }
  { loadA(11); bf8 bf = mk(b5x, b5y, 11 * 32 + 8 * q); domfma(bf); }
  { loadA(12); bf8 bf = mk(b0x, b0y, 12 * 32 + 8 * q); domfma(bf); }
  { loadA(13); bf8 bf = mk(b1x, b1y, 13 * 32 + 8 * q); domfma(bf); }
  { loadA(14); bf8 bf = mk(b2x, b2y, 14 * 32 + 8 * q); domfma(bf); }
  { loadA(15); bf8 bf = mk(b3x, b3y, 15 * 32 + 8 * q); domfma(bf); }

  // block-diag einsum step (y tiles): A from global (eps_y cols not staged)
  if (!IS_Z) {
    const bf8 dbf = cvt8_tril(dbx, dby, 8 * q, dI + lcol);
    const float* abase = eps + (size_t)lcol * DT + DZ + nb * 32 + 8 * q;
    float4 rx[4], ry[4];
    #pragma unroll
    for (int mi = 0; mi < 4; ++mi) {  // batch 1: rows 0..63
      const float* pa = abase + (size_t)mi * 16 * DT;
      rx[mi] = *(const float4*)pa; ry[mi] = *(const float4*)(pa + 4);
    }
    #pragma unroll
    for (int mi = 0; mi < 4; ++mi) {
      bf8 af = cvt8(rx[mi], ry[mi]);
      acc[mi] = __builtin_amdgcn_mfma_f32_16x16x32_bf16(af, dbf, acc[mi], 0, 0, 0);
    }
    #pragma unroll
    for (int mi = 0; mi < 4; ++mi) {  // batch 2: rows 64..127
      const float* pa = abase + (size_t)(mi + 4) * 16 * DT;
      rx[mi] = *(const float4*)pa; ry[mi] = *(const float4*)(pa + 4);
    }
    #pragma unroll
    for (int mi = 0; mi < 4; ++mi) {
      bf8 af = cvt8(rx[mi], ry[mi]);
      acc[mi + 4] = __builtin_amdgcn_mfma_f32_16x16x32_bf16(af, dbf, acc[mi + 4], 0, 0, 0);
    }
  }

  const float mval = mv[colL];
  #pragma unroll
  for (int mi = 0; mi < 8; ++mi) {
    #pragma unroll
    for (int r = 0; r < 4; ++r) {
      out[(size_t)(16 * mi + 4 * q + r) * DT + colL] = acc[mi][r] + mval;
    }
  }
}

// 256 blocks (1/CU) x 1024 threads (16 waves = 4/SIMD). Stage ALL of eps_z
// into LDS in MFMA-frag layout once; then each wave independently processes
// ONE 16-col tile (T = b*16 + wv), zero barriers after staging. Wave 15 of
// blocks 0..31 takes one extra tile (4096+b).
__global__ __launch_bounds__(1024, 4)
void sv_kernel(const float* __restrict__ mv, const float* __restrict__ Lz,
               const float* __restrict__ Ly, const float* __restrict__ Lyz,
               const float* __restrict__ eps, float* __restrict__ out) {
  // region r = kk*8+mi: slot==lane holds eps[16*mi+(lane&15)][kk*32+(lane>>4)*8..+7]
  __shared__ short Afrag[128 * 512];  // 128 KB

  const int tid = threadIdx.x;
  const int lane = tid & 63;
  const int wv = tid >> 6;
  const int lcol = lane & 15;
  const int q = lane >> 4;

  {  // stage eps_z once: wave-uniform region, slot=lane -> linear ds_write
    const int slot = lane;
    const int r0 = wv * 8;
    #pragma unroll 4
    for (int i = 0; i < 8; ++i) {
      const int r = r0 + i;  // 0..127; mi=r&7, kk=r>>3
      const float* p = eps + (size_t)(16 * (r & 7) + (slot & 15)) * DT +
                       (r >> 3) * 32 + (slot >> 4) * 8;
      float4 x = *(const float4*)p;
      float4 y = *(const float4*)(p + 4);
      *(bf8*)&Afrag[r * 512 + slot * 8] = cvt8(x, y);
    }
  }
  __syncthreads();  // the ONLY barrier

  {
    const int T = blockIdx.x * 16 + wv;  // 0..4095
    const int col0 = T * 16;
    if (col0 < DZ)
      process_tile<true>(col0, lcol, q, lane, Afrag, mv, Lz, Ly, Lyz, eps, out);
    else
      process_tile<false>(col0, lcol, q, lane, Afrag, mv, Lz, Ly, Lyz, eps, out);
  }
  if (wv == 15 && blockIdx.x < 32) {  // leftover tiles 4096..4127 (all y)
    const int col0 = (4096 + blockIdx.x) * 16;
    process_tile<false>(col0, lcol, q, lane, Afrag, mv, Lz, Ly, Lyz, eps, out);
  }
}

extern "C" void kernel_launch(void* const* d_in, const int* in_sizes, int n_in,
                              void* d_out, int out_size, void* d_ws, size_t ws_size,
                              hipStream_t stream) {
  const float* m   = (const float*)d_in[0];
  const float* Lz  = (const float*)d_in[1];
  const float* Ly  = (const float*)d_in[2];
  const float* Lyz = (const float*)d_in[3];
  const float* eps = (const float*)d_in[4];
  float* out = (float*)d_out;
  sv_kernel<<<dim3(256), dim3(1024), 0, stream>>>(m, Lz, Ly, Lyz, eps, out);
}